// Round 1
// baseline (268.343 us; speedup 1.0000x reference)
//
#include <hip/hip_runtime.h>
#include <math.h>

#define N_BINS 229
#define MODEL  128
#define OUTD   88
#define WSZ    30
#define WLEN   61
#define BB     4
#define TT     2048

__device__ __forceinline__ float fast_tanh(float x) {
    float ax = fabsf(x);
    float t  = __expf(-2.0f * ax);
    float r  = (1.0f - t) * __builtin_amdgcn_rcpf(1.0f + t);
    return copysignf(r, x);
}

// Pass 1: H = spec @ W_h + b_attn ; E = spec @ W_e
// one block per row r in [0, B*T), 256 threads: tid<128 -> H col, tid>=128 -> E col
__global__ __launch_bounds__(256) void k_he(
        const float* __restrict__ spec,
        const float* __restrict__ W_h,
        const float* __restrict__ W_e,
        const float* __restrict__ b_attn,
        float* __restrict__ H,
        float* __restrict__ E) {
    const int r   = blockIdx.x;
    const int tid = threadIdx.x;
    __shared__ float srow[N_BINS];
    for (int i = tid; i < N_BINS; i += 256)
        srow[i] = spec[(size_t)r * N_BINS + i];
    __syncthreads();

    const int m = tid & 127;
    const float* __restrict__ W = (tid < 128) ? W_h : W_e;
    float acc = (tid < 128) ? b_attn[m] : 0.0f;
#pragma unroll 4
    for (int f = 0; f < N_BINS; ++f)
        acc += srow[f] * W[f * MODEL + m];

    if (tid < 128) H[(size_t)r * MODEL + m] = acc;
    else           E[(size_t)r * MODEL + m] = acc;
}

// Pass 2: scores -> softmax -> weighted pooling -> W1 gemv + sigmoid
// one block per (b,t), 256 threads
__global__ __launch_bounds__(256) void k_attn(
        const float* __restrict__ spec,
        const float* __restrict__ H,
        const float* __restrict__ E,
        const float* __restrict__ v_w,
        const float* __restrict__ W1,
        const float* __restrict__ b1,
        float* __restrict__ pred,
        float* __restrict__ a_out) {
    const int r   = blockIdx.x;      // b*T + t
    const int b   = r >> 11;         // T = 2048
    const int t   = r & (TT - 1);
    const int tid = threadIdx.x;

    __shared__ float Hs[MODEL];
    __shared__ float vs[MODEL];
    __shared__ float sc[WLEN];
    __shared__ float a_sh[64];
    __shared__ float wsum[N_BINS];

    if (tid < MODEL) {
        Hs[tid] = H[(size_t)r * MODEL + tid];
        vs[tid] = v_w[tid];
    }
    __syncthreads();

    // ---- scores: 4 threads per window, 32 m-values each ----
    const int w  = tid >> 2;             // 0..63 (only 0..60 used)
    const int g  = tid & 3;              // quad lane
    const int mb = g * 32;
    const int s  = t + w - WSZ;
    const bool valid = (s >= 0 && s < TT);
    const float4* __restrict__ E4 =
        reinterpret_cast<const float4*>(E + ((size_t)(b * TT + (valid ? s : 0))) * MODEL + mb);

    float partial = 0.0f;
#pragma unroll
    for (int q = 0; q < 8; ++q) {
        const int qq = (q + g * 2) & 7;  // rotate to avoid LDS bank conflicts
        float4 ev = valid ? E4[qq] : make_float4(0.f, 0.f, 0.f, 0.f);
        const int m0 = mb + qq * 4;
        partial += fast_tanh(Hs[m0 + 0] + ev.x) * vs[m0 + 0];
        partial += fast_tanh(Hs[m0 + 1] + ev.y) * vs[m0 + 1];
        partial += fast_tanh(Hs[m0 + 2] + ev.z) * vs[m0 + 2];
        partial += fast_tanh(Hs[m0 + 3] + ev.w) * vs[m0 + 3];
    }
    partial += __shfl_xor(partial, 1, 64);
    partial += __shfl_xor(partial, 2, 64);
    if (g == 0 && w < WLEN) sc[w] = partial;
    __syncthreads();

    // ---- softmax over 61 scores (wave 0) ----
    if (tid < 64) {
        float x = (tid < WLEN) ? sc[tid] : -INFINITY;
        float mx = x;
#pragma unroll
        for (int d = 32; d >= 1; d >>= 1) mx = fmaxf(mx, __shfl_xor(mx, d, 64));
        float e = (tid < WLEN) ? __expf(x - mx) : 0.0f;
        float sm = e;
#pragma unroll
        for (int d = 32; d >= 1; d >>= 1) sm += __shfl_xor(sm, d, 64);
        float a = e * __builtin_amdgcn_rcpf(sm);
        a_sh[tid] = a;
        if (tid < WLEN) a_out[(size_t)r * WLEN + tid] = a;
    }
    __syncthreads();

    // ---- weighted pooling over the window ----
    if (tid < N_BINS) {
        float acc = 0.0f;
        for (int w2 = 0; w2 < WLEN; ++w2) {
            const int s2 = t + w2 - WSZ;
            if (s2 >= 0 && s2 < TT)
                acc += a_sh[w2] * spec[((size_t)(b * TT + s2)) * N_BINS + tid];
        }
        wsum[tid] = acc;
    }
    __syncthreads();

    // ---- output gemv + sigmoid ----
    if (tid < OUTD) {
        float acc = b1[tid];
#pragma unroll 4
        for (int f = 0; f < N_BINS; ++f)
            acc += wsum[f] * W1[f * OUTD + tid];
        float o = __builtin_amdgcn_rcpf(1.0f + __expf(-acc));
        pred[(size_t)r * OUTD + tid] = o;
    }
}

extern "C" void kernel_launch(void* const* d_in, const int* in_sizes, int n_in,
                              void* d_out, int out_size, void* d_ws, size_t ws_size,
                              hipStream_t stream) {
    const float* spec   = (const float*)d_in[0];
    const float* W_h    = (const float*)d_in[1];
    const float* W_e    = (const float*)d_in[2];
    const float* b_attn = (const float*)d_in[3];
    const float* v_w    = (const float*)d_in[4];
    const float* W1     = (const float*)d_in[5];
    const float* b1     = (const float*)d_in[6];

    const int n_rows = BB * TT;                 // 8192
    float* H = (float*)d_ws;                    // n_rows*128 floats = 4 MB
    float* E = H + (size_t)n_rows * MODEL;      // n_rows*128 floats = 4 MB

    float* pred  = (float*)d_out;                       // B*T*88
    float* a_out = pred + (size_t)n_rows * OUTD;        // B*T*61

    k_he<<<n_rows, 256, 0, stream>>>(spec, W_h, W_e, b_attn, H, E);
    k_attn<<<n_rows, 256, 0, stream>>>(spec, H, E, v_w, W1, b1, pred, a_out);
}

// Round 2
// 141.290 us; speedup vs baseline: 1.8992x; 1.8992x over previous
//
#include <hip/hip_runtime.h>
#include <math.h>

#define N_BINS 229
#define MODEL  128
#define OUTD   88
#define WSZ    30
#define WLEN   61
#define BB     4
#define TT     2048

__device__ __forceinline__ float fast_tanh(float x) {
    float ax = fabsf(x);
    float t  = __expf(-2.0f * ax);
    float r  = (1.0f - t) * __builtin_amdgcn_rcpf(1.0f + t);
    return copysignf(r, x);
}

__device__ __forceinline__ float sigmoidf_(float x) {
    return __builtin_amdgcn_rcpf(1.0f + __expf(-x));
}

// ---------------- Pass 1: H = spec@W_h + b_attn ; E = spec@W_e ----------------
// 8 rows per block; spec tile staged in LDS; thread = output column (128 H + 128 E),
// 8 accumulators so each W load is amortized over 8 FMAs.
#define ROWS_HE 8
__global__ __launch_bounds__(256) void k_he(
        const float* __restrict__ spec,
        const float* __restrict__ W_h,
        const float* __restrict__ W_e,
        const float* __restrict__ b_attn,
        float* __restrict__ H,
        float* __restrict__ E) {
    const int tid = threadIdx.x;
    __shared__ float s[ROWS_HE * N_BINS];          // 1832 floats, contiguous in global
    const float4* __restrict__ src4 =
        (const float4*)(spec + (size_t)blockIdx.x * (ROWS_HE * N_BINS));
    float4* s4 = (float4*)s;
#pragma unroll
    for (int i = 0; i < 2; ++i) {                  // 458 float4 / 256 threads
        int idx = i * 256 + tid;
        if (idx < (ROWS_HE * N_BINS) / 4) s4[idx] = src4[idx];
    }
    __syncthreads();

    const int  m   = tid & 127;
    const bool isH = tid < 128;
    const float* __restrict__ Wp = (isH ? W_h : W_e) + m;
    const float bias = isH ? b_attn[m] : 0.0f;

    float acc[ROWS_HE];
#pragma unroll
    for (int r = 0; r < ROWS_HE; ++r) acc[r] = 0.0f;

#pragma unroll 4
    for (int f = 0; f < N_BINS; ++f) {
        float wv = Wp[f * MODEL];
#pragma unroll
        for (int r = 0; r < ROWS_HE; ++r)
            acc[r] = fmaf(s[r * N_BINS + f], wv, acc[r]);
    }

    float* __restrict__ dst =
        (isH ? H : E) + (size_t)blockIdx.x * ROWS_HE * MODEL + m;
#pragma unroll
    for (int r = 0; r < ROWS_HE; ++r) dst[r * MODEL] = acc[r] + bias;
}

// ---------------- Pass 2: scores -> softmax -> pooling -> gemv ----------------
// One WAVE per row (4 rows/block). No cross-wave sync until the final gemv.
__global__ __launch_bounds__(256) void k_attn(
        const float* __restrict__ spec,
        const float* __restrict__ H,
        const float* __restrict__ E,
        const float* __restrict__ v_w,
        const float* __restrict__ W1,
        const float* __restrict__ b1,
        float* __restrict__ pred,
        float* __restrict__ a_out) {
    const int tid  = threadIdx.x;
    const int wv   = tid >> 6;
    const int lane = tid & 63;
    const int r    = blockIdx.x * 4 + wv;
    const int b    = r >> 11;                      // T = 2048
    const int t    = r & (TT - 1);

    __shared__ float sc[4][64];
    __shared__ float aEff[4][64];
    __shared__ float wsum[4][232];

    // ---- per-lane H / v_w fragments in registers (no LDS in tanh loop) ----
    const int g = lane & 3, mb = g * 32;
    float4 hv[8], vv[8];
    const float4* __restrict__ Hp = (const float4*)(H + (size_t)r * MODEL + mb);
    const float4* __restrict__ Vp = (const float4*)(v_w + mb);
#pragma unroll
    for (int q = 0; q < 8; ++q) { hv[q] = Hp[q]; vv[q] = Vp[q]; }

    // ---- scores: quad of lanes per window, 16 windows per iteration ----
    const int w0 = lane >> 2;
    const float* __restrict__ Eb = E + (size_t)b * TT * MODEL;
#pragma unroll
    for (int it = 0; it < 4; ++it) {
        const int  w   = w0 + it * 16;             // 0..63
        const int  s   = t + w - WSZ;
        const bool val = (w < WLEN) && (s >= 0) && (s < TT);
        const int  sCl = min(max(s, 0), TT - 1);
        const float4* __restrict__ E4 =
            (const float4*)(Eb + (size_t)sCl * MODEL + mb);
        float p = 0.0f;
#pragma unroll
        for (int q = 0; q < 8; ++q) {
            float4 ev = E4[q];
            if (!val) ev = make_float4(0.f, 0.f, 0.f, 0.f);
            p += fast_tanh(hv[q].x + ev.x) * vv[q].x;
            p += fast_tanh(hv[q].y + ev.y) * vv[q].y;
            p += fast_tanh(hv[q].z + ev.z) * vv[q].z;
            p += fast_tanh(hv[q].w + ev.w) * vv[q].w;
        }
        p += __shfl_xor(p, 1, 64);
        p += __shfl_xor(p, 2, 64);
        if (g == 0) sc[wv][w] = p;
    }

    // ---- wave-local softmax over 61 scores ----
    float x = (lane < WLEN) ? sc[wv][lane] : -INFINITY;
    float mx = x;
#pragma unroll
    for (int d = 32; d >= 1; d >>= 1) mx = fmaxf(mx, __shfl_xor(mx, d, 64));
    float e = (lane < WLEN) ? __expf(x - mx) : 0.0f;
    float sm = e;
#pragma unroll
    for (int d = 32; d >= 1; d >>= 1) sm += __shfl_xor(sm, d, 64);
    float a = e * __builtin_amdgcn_rcpf(sm);
    const int sl = t + lane - WSZ;
    aEff[wv][lane] = (sl >= 0 && sl < TT) ? a : 0.0f;   // zero for zero-padded rows
    if (lane < WLEN) a_out[(size_t)r * WLEN + lane] = a;

    // ---- pooling: lane owns 4 f-columns; 4 independent loads / iter ----
    const float* __restrict__ sb = spec + (size_t)b * TT * N_BINS;
    float a0 = 0.f, a1 = 0.f, a2 = 0.f, a3 = 0.f;
    const int f3 = (lane < 37) ? lane + 192 : 228;
#pragma unroll 8
    for (int w2 = 0; w2 < WLEN; ++w2) {
        float av = aEff[wv][w2];                   // LDS broadcast
        int   s2 = min(max(t + w2 - WSZ, 0), TT - 1);
        const float* __restrict__ row = sb + (size_t)s2 * N_BINS;
        a0 = fmaf(av, row[lane      ], a0);
        a1 = fmaf(av, row[lane +  64], a1);
        a2 = fmaf(av, row[lane + 128], a2);
        a3 = fmaf(av, row[f3        ], a3);
    }
    wsum[wv][lane      ] = a0;
    wsum[wv][lane +  64] = a1;
    wsum[wv][lane + 128] = a2;
    if (lane < 37) wsum[wv][lane + 192] = a3;

    __syncthreads();

    // ---- gemv + sigmoid: 176 threads, each does 2 rows (W1 shared 4x) ----
    if (tid < 176) {
        const int h  = (tid >= 88) ? 1 : 0;
        const int o  = tid - (h ? 88 : 0);
        const int rw = 2 * h;
        float acc0 = b1[o], acc1 = acc0;
        const float* __restrict__ W1o = W1 + o;
#pragma unroll 4
        for (int f = 0; f < N_BINS; ++f) {
            float w1 = W1o[f * OUTD];
            acc0 = fmaf(wsum[rw    ][f], w1, acc0);
            acc1 = fmaf(wsum[rw + 1][f], w1, acc1);
        }
        const size_t r0 = (size_t)blockIdx.x * 4 + rw;
        pred[r0 * OUTD + o]       = sigmoidf_(acc0);
        pred[(r0 + 1) * OUTD + o] = sigmoidf_(acc1);
    }
}

extern "C" void kernel_launch(void* const* d_in, const int* in_sizes, int n_in,
                              void* d_out, int out_size, void* d_ws, size_t ws_size,
                              hipStream_t stream) {
    const float* spec   = (const float*)d_in[0];
    const float* W_h    = (const float*)d_in[1];
    const float* W_e    = (const float*)d_in[2];
    const float* b_attn = (const float*)d_in[3];
    const float* v_w    = (const float*)d_in[4];
    const float* W1     = (const float*)d_in[5];
    const float* b1     = (const float*)d_in[6];

    const int n_rows = BB * TT;                    // 8192
    float* H = (float*)d_ws;                       // 4 MB
    float* E = H + (size_t)n_rows * MODEL;         // 4 MB

    float* pred  = (float*)d_out;                  // 8192*88
    float* a_out = pred + (size_t)n_rows * OUTD;   // 8192*61

    k_he  <<<n_rows / ROWS_HE, 256, 0, stream>>>(spec, W_h, W_e, b_attn, H, E);
    k_attn<<<n_rows / 4,       256, 0, stream>>>(spec, H, E, v_w, W1, b1, pred, a_out);
}